// Round 1
// baseline (445.521 us; speedup 1.0000x reference)
//
#include <hip/hip_runtime.h>
#include <cstddef>

// ---------------------------------------------------------------------------
// Fused equivariant decoder, MI355X (gfx950).
// Structure: e3linear is block-diagonal in l; gates couple only through the
// l=0 (scalar) chain. Per 8-row tile: scalar chain first (produces gate
// vectors G1..G3 in LDS), then six independent l>0 chains of 3 MFMA GEMMs +
// final dot. f16 MFMA (16x16x32), fp32 accum. Weights pre-packed into exact
// B-fragment order (W^T * 1/sqrt(K)) in d_ws by a prep kernel.
// ---------------------------------------------------------------------------

typedef _Float16 half8 __attribute__((ext_vector_type(8)));
typedef float    f32x4 __attribute__((ext_vector_type(4)));
typedef float    fvec4 __attribute__((ext_vector_type(4)));

#define B_ROWS  8
#define IN_DIM  3840
#define OUT_COLS 49

// LDS map (elements of _Float16); all offsets divisible by 8 -> 16B aligned.
#define OFF_STG0 0
#define OFF_STG1 8064
#define OFF_H0   16128
#define OFF_H1   20608
#define OFF_G1   25088
#define OFF_G2   27200
#define OFF_G3   29312
#define SMEM_ELTS 31424   // * 2B = 62848 B < 64 KiB -> 2 wg/CU

// Packed-weight region bases (elements) in d_ws
#define P2BASE 106496
#define P3BASE 139264

// ---------------------------------------------------------------------------
// Weight prep: for every (layer, l-block), emit B-fragments of W^T / sqrt(K).
// Fragment f = (nt*KF + kf)*64 + lane holds 8 elems: B[k][n] with
// k = kf*32 + (lane>>4)*8 + j,  n = nt*16 + (lane&15).  B[k][n] = w[woff+k*N+n].
// ---------------------------------------------------------------------------
__global__ __launch_bounds__(256) void prep_weights(
    const float* __restrict__ w1, const float* __restrict__ w2,
    const float* __restrict__ w3, _Float16* __restrict__ packed)
{
  const int g = blockIdx.x * 256 + threadIdx.x;   // 0 .. 21503 (172032/8 frags)
  const int K_[24]    = {256,256,128,128,64,64,64,64,  64,64,64,64,32,32,32,32,
                         64,64,64,64,32,32,32,32};
  const int N_[24]    = {64,256,64,64,32,32,32,32,  64,256,64,64,32,32,32,32,
                         64,256,64,64,32,32,32,32};
  const int woff_[24] = {0,16384,81920,90112,98304,100352,102400,104448,
                         0,4096,20480,24576,28672,29696,30720,31744,
                         0,4096,20480,24576,28672,29696,30720,31744};
  const int poff_[24] = {0,16384,81920,90112,98304,100352,102400,104448,
                         106496,110592,126976,131072,135168,136192,137216,138240,
                         139264,143360,159744,163840,167936,168960,169984,171008};
  int bi = 0;
  for (int i = 1; i < 24; ++i) if (g * 8 >= poff_[i]) bi = i;
  const float* w = (bi < 8) ? w1 : ((bi < 16) ? w2 : w3);
  const int rel8 = g - poff_[bi] / 8;
  const int lane = rel8 & 63;
  const int fi   = rel8 >> 6;
  const int K = K_[bi], N = N_[bi];
  const int KF = K >> 5;
  const int kf = fi % KF;
  const int nt = fi / KF;
  const int k0 = kf * 32 + (lane >> 4) * 8;
  const int n  = nt * 16 + (lane & 15);
  const float scale = 1.0f / sqrtf((float)K);
  half8 vv;
#pragma unroll
  for (int j = 0; j < 8; ++j)
    vv[j] = (_Float16)(w[woff_[bi] + (size_t)(k0 + j) * N + n] * scale);
  *(half8*)(packed + (size_t)g * 8) = vv;
}

// ---------------------------------------------------------------------------
// Input staging: coalesced float4 global loads into registers (issued early,
// consumed later -> HBM latency overlaps previous chain's compute), then
// f16-convert + transpose-scatter into LDS A-layout: stg[(b*(2l+1)+m)][i],
// pitch K+8.
// ---------------------------------------------------------------------------
template<int TWOL1, int MUL>
__device__ __forceinline__ void issue_loads(const float* __restrict__ vraw,
                                            int b0, int inoff, fvec4 (&regs)[7])
{
  constexpr int D  = MUL * TWOL1;
  constexpr int D4 = D / 4;
  constexpr int V4 = D4 * B_ROWS;
  constexpr int NV = (V4 + 255) / 256;
  const int t = threadIdx.x;
#pragma unroll
  for (int v = 0; v < NV; ++v) {
    const int gv = v * 256 + t;
    if ((V4 & 255) == 0 || gv < V4) {
      const int b  = gv / D4;
      const int dd = (gv - b * D4) * 4;
      regs[v] = *(const fvec4*)(vraw + (size_t)(b0 + b) * IN_DIM + inoff + dd);
    }
  }
}

template<int TWOL1, int MUL>
__device__ __forceinline__ void write_stage(const fvec4 (&regs)[7], _Float16* stg)
{
  constexpr int D  = MUL * TWOL1;
  constexpr int D4 = D / 4;
  constexpr int V4 = D4 * B_ROWS;
  constexpr int NV = (V4 + 255) / 256;
  constexpr int KP = MUL + 8;
  const int t = threadIdx.x;
#pragma unroll
  for (int v = 0; v < NV; ++v) {
    const int gv = v * 256 + t;
    if ((V4 & 255) == 0 || gv < V4) {
      const int b  = gv / D4;
      const int dd = (gv - b * D4) * 4;
      const fvec4 x = regs[v];
#pragma unroll
      for (int j = 0; j < 4; ++j) {
        const int d = dd + j;
        const int i = d / TWOL1;          // constexpr divisor -> magic mul
        const int m = d - i * TWOL1;
        stg[(b * TWOL1 + m) * KP + i] = (_Float16)x[j];
      }
    }
  }
}

// ---------------------------------------------------------------------------
// GEMM + gate epilogue for l>0 blocks.
// A: LDS, rows=(b,m) (R=8*(2l+1), tiles padded to 16), i contiguous, pitch K+8
// B: packed frags in global (L2-resident)
// C rows: row = mt*16 + (lane>>4)*4 + r ; col = nt*16 + (lane&15)   [verified]
// ---------------------------------------------------------------------------
template<int TWOL1, int K, int N>
__device__ __forceinline__ void gemm_gated(
    const _Float16* __restrict__ A, const _Float16* __restrict__ Bp,
    _Float16* __restrict__ H, const _Float16* __restrict__ G, int goff)
{
  constexpr int R  = 8 * TWOL1;
  constexpr int MT = (R + 15) / 16;
  constexpr int NT = N / 16;
  constexpr int KF = K / 32;
  constexpr int AP = K + 8;
  constexpr int HP = N + 8;
  const int lane = threadIdx.x & 63;
  const int wave = threadIdx.x >> 6;
  const int col  = lane & 15;
  const int quad = lane >> 4;
  for (int t = wave; t < MT * NT; t += 4) {
    const int mt = t % MT;
    const int nt = t / MT;
    f32x4 acc = {0.f, 0.f, 0.f, 0.f};
    const _Float16* ap = A + (mt * 16 + col) * AP + quad * 8;
    const _Float16* bp = Bp + ((size_t)(nt * KF * 64 + lane)) * 8;
#pragma unroll
    for (int kf = 0; kf < KF; ++kf) {
      const half8 av = *(const half8*)(ap + kf * 32);
      const half8 bv = *(const half8*)(bp + kf * 512);
      acc = __builtin_amdgcn_mfma_f32_16x16x32_f16(av, bv, acc, 0, 0, 0);
    }
    const int o = nt * 16 + col;
#pragma unroll
    for (int r = 0; r < 4; ++r) {
      const int row = mt * 16 + quad * 4 + r;
      if (row < R) {
        const int b = row / TWOL1;
        const float gg = (float)G[b * 264 + goff + o];
        H[row * HP + o] = (_Float16)(acc[r] * gg);
      }
    }
  }
}

// ---------------------------------------------------------------------------
// Scalar-chain GEMM (l=0): N=64 silu part -> Hs, N=256 sigmoid part -> G.
// M = 8 rows (one 16-tile, rows 8..15 garbage, guarded).
// ---------------------------------------------------------------------------
template<int K>
__device__ __forceinline__ void gemm_scal(
    const _Float16* __restrict__ A, const _Float16* __restrict__ Bs,
    const _Float16* __restrict__ Bg, _Float16* __restrict__ Hs,
    _Float16* __restrict__ Gout)
{
  constexpr int KF = K / 32;
  constexpr int AP = K + 8;
  const int lane = threadIdx.x & 63;
  const int wave = threadIdx.x >> 6;
  const int col  = lane & 15;
  const int quad = lane >> 4;
  const _Float16* ap0 = A + col * AP + quad * 8;
  {                                      // silu part, N=64: one tile per wave
    const int nt = wave;
    f32x4 acc = {0.f, 0.f, 0.f, 0.f};
    const _Float16* bp = Bs + ((size_t)(nt * KF * 64 + lane)) * 8;
#pragma unroll
    for (int kf = 0; kf < KF; ++kf)
      acc = __builtin_amdgcn_mfma_f32_16x16x32_f16(
          *(const half8*)(ap0 + kf * 32), *(const half8*)(bp + kf * 512), acc, 0, 0, 0);
    const int o = nt * 16 + col;
#pragma unroll
    for (int r = 0; r < 4; ++r) {
      const int row = quad * 4 + r;
      if (row < B_ROWS) {
        const float z  = acc[r];
        const float sg = 1.f / (1.f + __expf(-z));
        Hs[row * 72 + o] = (_Float16)(z * sg);
      }
    }
  }
  for (int nt = wave; nt < 16; nt += 4) { // gate part, N=256 -> sigmoid
    f32x4 acc = {0.f, 0.f, 0.f, 0.f};
    const _Float16* bp = Bg + ((size_t)(nt * KF * 64 + lane)) * 8;
#pragma unroll
    for (int kf = 0; kf < KF; ++kf)
      acc = __builtin_amdgcn_mfma_f32_16x16x32_f16(
          *(const half8*)(ap0 + kf * 32), *(const half8*)(bp + kf * 512), acc, 0, 0, 0);
    const int o = nt * 16 + col;
#pragma unroll
    for (int r = 0; r < 4; ++r) {
      const int row = quad * 4 + r;
      if (row < B_ROWS)
        Gout[row * 264 + o] = (_Float16)(1.f / (1.f + __expf(-acc[r])));
    }
  }
}

// Final layer: per-row dot with w4 (f32, uniform -> scalar loads), N=1.
template<int TWOL1, int K>
__device__ __forceinline__ void layer4(
    const _Float16* __restrict__ H, const float* __restrict__ w4, int w4off,
    float* __restrict__ out, int b0, int lsq)
{
  constexpr int R  = 8 * TWOL1;
  constexpr int HP = K + 8;
  const int r = threadIdx.x;
  if (r < R) {
    float s = 0.f;
#pragma unroll
    for (int i = 0; i < K; ++i) s += (float)H[r * HP + i] * w4[w4off + i];
    constexpr float scale = (K == 64) ? 0.125f : 0.17677669529663687f;
    const int b = r / TWOL1;
    const int m = r - b * TWOL1;
    out[(size_t)(b0 + b) * OUT_COLS + lsq + m] = s * scale;
  }
}

__device__ __forceinline__ void compute_chain0(
    const _Float16* stg, _Float16* H0, _Float16* H1,
    _Float16* G1, _Float16* G2, _Float16* G3,
    const _Float16* packed, const float* w4, float* out, int b0)
{
  gemm_scal<256>(stg, packed + 0,          packed + 16384,        H0, G1);
  __syncthreads();
  gemm_scal<64>(H0,  packed + P2BASE + 0,  packed + P2BASE + 4096, H1, G2);
  __syncthreads();
  gemm_scal<64>(H1,  packed + P3BASE + 0,  packed + P3BASE + 4096, H0, G3);
  __syncthreads();
  layer4<1, 64>(H0, w4, 0, out, b0, 0);
}

template<int L>
__device__ __forceinline__ void compute_chain(
    const _Float16* stg, _Float16* H0, _Float16* H1,
    const _Float16* G1, const _Float16* G2, const _Float16* G3,
    const _Float16* packed, const float* w4, float* out, int b0)
{
  constexpr int TWOL1 = 2 * L + 1;
  constexpr int K1 = (L <= 2) ? 128 : 64;
  constexpr int N1 = (L <= 2) ? 64 : 32;
  constexpr int P1OFF[7] = {0, 81920, 90112, 98304, 100352, 102400, 104448};
  constexpr int P2REL[7] = {0, 20480, 24576, 28672, 29696, 30720, 31744};
  constexpr int GOFF[7]  = {0, 0, 64, 128, 160, 192, 224};
  constexpr int W4OFF[7] = {0, 64, 128, 192, 224, 256, 288};
  gemm_gated<TWOL1, K1, N1>(stg, packed + P1OFF[L],          H0, G1, GOFF[L]);
  __syncthreads();
  gemm_gated<TWOL1, N1, N1>(H0,  packed + P2BASE + P2REL[L], H1, G2, GOFF[L]);
  __syncthreads();
  gemm_gated<TWOL1, N1, N1>(H1,  packed + P3BASE + P2REL[L], H0, G3, GOFF[L]);
  __syncthreads();
  layer4<TWOL1, N1>(H0, w4, W4OFF[L], out, b0, L * L);
}

__global__ __launch_bounds__(256) void fused_decoder(
    const float* __restrict__ vraw, const float* __restrict__ w4,
    const _Float16* __restrict__ packed, float* __restrict__ out)
{
  __shared__ __align__(16) _Float16 smem[SMEM_ELTS];
  _Float16* stg0 = smem + OFF_STG0;
  _Float16* stg1 = smem + OFF_STG1;
  _Float16* H0   = smem + OFF_H0;
  _Float16* H1   = smem + OFF_H1;
  _Float16* G1   = smem + OFF_G1;
  _Float16* G2   = smem + OFF_G2;
  _Float16* G3   = smem + OFF_G3;
  const int b0 = blockIdx.x * B_ROWS;
  fvec4 rA[7], rB[7];

  issue_loads<1, 256>(vraw, b0, 0, rA);     // chain 0 (l=0)
  issue_loads<3, 128>(vraw, b0, 256, rB);   // chain 1 in flight early
  write_stage<1, 256>(rA, stg0);
  __syncthreads();
  compute_chain0(stg0, H0, H1, G1, G2, G3, packed, w4, out, b0);

  write_stage<3, 128>(rB, stg1);
  issue_loads<5, 128>(vraw, b0, 640, rA);
  __syncthreads();
  compute_chain<1>(stg1, H0, H1, G1, G2, G3, packed, w4, out, b0);

  write_stage<5, 128>(rA, stg0);
  issue_loads<7, 64>(vraw, b0, 1280, rB);
  __syncthreads();
  compute_chain<2>(stg0, H0, H1, G1, G2, G3, packed, w4, out, b0);

  write_stage<7, 64>(rB, stg1);
  issue_loads<9, 64>(vraw, b0, 1728, rA);
  __syncthreads();
  compute_chain<3>(stg1, H0, H1, G1, G2, G3, packed, w4, out, b0);

  write_stage<9, 64>(rA, stg0);
  issue_loads<11, 64>(vraw, b0, 2304, rB);
  __syncthreads();
  compute_chain<4>(stg0, H0, H1, G1, G2, G3, packed, w4, out, b0);

  write_stage<11, 64>(rB, stg1);
  issue_loads<13, 64>(vraw, b0, 3008, rA);
  __syncthreads();
  compute_chain<5>(stg1, H0, H1, G1, G2, G3, packed, w4, out, b0);

  write_stage<13, 64>(rA, stg0);
  __syncthreads();
  compute_chain<6>(stg0, H0, H1, G1, G2, G3, packed, w4, out, b0);
}

extern "C" void kernel_launch(void* const* d_in, const int* in_sizes, int n_in,
                              void* d_out, int out_size, void* d_ws, size_t ws_size,
                              hipStream_t stream)
{
  (void)in_sizes; (void)n_in; (void)out_size; (void)ws_size;
  const float* vraw = (const float*)d_in[0];
  const float* w1   = (const float*)d_in[1];
  const float* w2   = (const float*)d_in[2];
  const float* w3   = (const float*)d_in[3];
  const float* w4   = (const float*)d_in[4];
  float* out = (float*)d_out;
  _Float16* packed = (_Float16*)d_ws;   // 172032 elems = 344064 B

  prep_weights<<<84, 256, 0, stream>>>(w1, w2, w3, packed);
  fused_decoder<<<16384 / B_ROWS, 256, 0, stream>>>(vraw, w4, packed, out);
}

// Round 2
// 391.070 us; speedup vs baseline: 1.1392x; 1.1392x over previous
//
#include <hip/hip_runtime.h>
#include <cstddef>

// ---------------------------------------------------------------------------
// Fused equivariant decoder, MI355X (gfx950) — round 2.
// Swapped-operand MFMA: weights are the A operand, activations the B operand,
// so D[o][(b,m)]. C-lanes hold 4 consecutive o for one (b,m) column ->
// vectorized gate (half4 load + mul), vectorized H writes (ds_write_b64),
// vectorized next-layer B reads (ds_read_b128), vectorized layer4.
// Single staging buffer, H ping-pong across chains, 51.3KB LDS -> 3 wg/CU.
// ---------------------------------------------------------------------------

typedef _Float16 half8 __attribute__((ext_vector_type(8)));
typedef _Float16 half4 __attribute__((ext_vector_type(4)));
typedef float    f32x4 __attribute__((ext_vector_type(4)));
typedef float    fvec4 __attribute__((ext_vector_type(4)));

#define B_ROWS   8
#define IN_DIM   3840
#define OUT_COLS 49

// LDS map (elements of _Float16), all 16B aligned.
#define OFF_STG  0        // 8064  (max: l=6 staged 112x72)
#define OFF_HA   8064     // 4480  (max: l=6 H 112x40)
#define OFF_HB   12544    // 4480
#define OFF_HSA  17024    // 1152  (16x72 scalar hidden)
#define OFF_HSB  18176    // 1152
#define OFF_G1   19328    // 2112  (8x264)
#define OFF_G2   21440    // 2112
#define OFF_G3   23552    // 2112
#define SMEM_ELTS 25664   // *2B = 51328 B -> 3 wg/CU

// Packed-weight region bases (elements) in d_ws
#define P2BASE 106496
#define P3BASE 139264

// ---------------------------------------------------------------------------
// Weight prep (unchanged packing math; now consumed as A-fragments).
// Frag f=(mt*KF+kf)*64+lane holds 8 elems W[i][o]*scale with
// i=kf*32+(lane>>4)*8+j, o=mt*16+(lane&15).
// static const arrays -> constant memory, no scratch.
// ---------------------------------------------------------------------------
__global__ __launch_bounds__(256) void prep_weights(
    const float* __restrict__ w1, const float* __restrict__ w2,
    const float* __restrict__ w3, _Float16* __restrict__ packed)
{
  static const int K_[24]    = {256,256,128,128,64,64,64,64,  64,64,64,64,32,32,32,32,
                                64,64,64,64,32,32,32,32};
  static const int N_[24]    = {64,256,64,64,32,32,32,32,  64,256,64,64,32,32,32,32,
                                64,256,64,64,32,32,32,32};
  static const int woff_[24] = {0,16384,81920,90112,98304,100352,102400,104448,
                                0,4096,20480,24576,28672,29696,30720,31744,
                                0,4096,20480,24576,28672,29696,30720,31744};
  static const int poff_[24] = {0,16384,81920,90112,98304,100352,102400,104448,
                                106496,110592,126976,131072,135168,136192,137216,138240,
                                139264,143360,159744,163840,167936,168960,169984,171008};
  const int g = blockIdx.x * 256 + threadIdx.x;   // 0 .. 21503
  int bi = 0;
#pragma unroll
  for (int i = 1; i < 24; ++i) if (g * 8 >= poff_[i]) bi = i;
  const float* w = (bi < 8) ? w1 : ((bi < 16) ? w2 : w3);
  const int rel8 = g - poff_[bi] / 8;
  const int lane = rel8 & 63;
  const int fi   = rel8 >> 6;
  const int K = K_[bi], N = N_[bi];
  const int KF = K >> 5;
  const int kf = fi % KF;
  const int mt = fi / KF;
  const int k0 = kf * 32 + (lane >> 4) * 8;
  const int o  = mt * 16 + (lane & 15);
  const float scale = 1.0f / sqrtf((float)K);
  half8 vv;
#pragma unroll
  for (int j = 0; j < 8; ++j)
    vv[j] = (_Float16)(w[woff_[bi] + (size_t)(k0 + j) * N + o] * scale);
  *(half8*)(packed + (size_t)g * 8) = vv;
}

// ---------------------------------------------------------------------------
// Input staging. Loads: coalesced float4 into registers (issued ~3 barriers
// before consumption). write_stage scatters into B-layout: stg[(b,m)][i],
// pitch MUL+8, i contiguous -> ds_read_b128 fragments.
// ---------------------------------------------------------------------------
template<int TWOL1, int MUL>
__device__ __forceinline__ void issue_loads(const float* __restrict__ vraw,
                                            int b0, int inoff, fvec4 (&regs)[7])
{
  constexpr int D  = MUL * TWOL1;
  constexpr int D4 = D / 4;
  constexpr int V4 = D4 * B_ROWS;
  constexpr int NV = (V4 + 255) / 256;
  const int t = threadIdx.x;
#pragma unroll
  for (int v = 0; v < NV; ++v) {
    const int gv = v * 256 + t;
    if ((V4 & 255) == 0 || gv < V4) {
      const int b  = gv / D4;
      const int dd = (gv - b * D4) * 4;
      regs[v] = *(const fvec4*)(vraw + (size_t)(b0 + b) * IN_DIM + inoff + dd);
    }
  }
}

template<int TWOL1, int MUL>
__device__ __forceinline__ void write_stage(const fvec4 (&regs)[7], _Float16* stg)
{
  constexpr int D  = MUL * TWOL1;
  constexpr int D4 = D / 4;
  constexpr int V4 = D4 * B_ROWS;
  constexpr int NV = (V4 + 255) / 256;
  constexpr int KP = MUL + 8;
  const int t = threadIdx.x;
#pragma unroll
  for (int v = 0; v < NV; ++v) {
    const int gv = v * 256 + t;
    if ((V4 & 255) == 0 || gv < V4) {
      const int b  = gv / D4;
      const int dd = (gv - b * D4) * 4;
      const fvec4 x = regs[v];
#pragma unroll
      for (int j = 0; j < 4; ++j) {
        const int d = dd + j;
        const int i = d / TWOL1;
        const int m = d - i * TWOL1;
        stg[(b * TWOL1 + m) * KP + i] = (_Float16)x[j];
      }
    }
  }
}

// l=0 staging: i contiguous per row -> vector half4 LDS writes.
__device__ __forceinline__ void ws_l0(const fvec4 (&regs)[7], _Float16* stg)
{
  const int t = threadIdx.x;
#pragma unroll
  for (int v = 0; v < 2; ++v) {
    const int gv = v * 256 + t;       // < 512
    const int b  = gv >> 6;
    const int i0 = (gv & 63) * 4;
    const fvec4 x = regs[v];
    half4 h;
#pragma unroll
    for (int j = 0; j < 4; ++j) h[j] = (_Float16)x[j];
    *(half4*)(stg + b * 264 + i0) = h;
  }
}

// ---------------------------------------------------------------------------
// Swapped GEMM + gate for l>0: D[o][(b,m)] = sum_i W^T[o][i] * X[(b,m)][i].
// A = packed weight frags (global, L2-hot). B = activations (LDS, b128).
// C lanes: o = mt*16 + quad*4 + r (rows), c=(b,m) = nt*16 + (lane&15) (col).
// Epilogue: half4 G load, f16 gate mul, ds_write_b64 to H[c][o].
// ---------------------------------------------------------------------------
template<int TWOL1, int K, int N>
__device__ __forceinline__ void gemm_sw(
    const _Float16* __restrict__ Bact, const _Float16* __restrict__ Ap,
    _Float16* __restrict__ H, const _Float16* __restrict__ G, int goff)
{
  constexpr int R  = 8 * TWOL1;
  constexpr int NT = (R + 15) / 16;
  constexpr int MT = N / 16;
  constexpr int KF = K / 32;
  constexpr int AP = K + 8;
  constexpr int HP = N + 8;
  const int lane = threadIdx.x & 63;
  const int wave = threadIdx.x >> 6;
  const int col  = lane & 15;
  const int quad = lane >> 4;
  for (int t = wave; t < MT * NT; t += 4) {
    const int mt = t % MT;
    const int nt = t / MT;
    f32x4 acc = {0.f, 0.f, 0.f, 0.f};
    const _Float16* bp = Bact + (nt * 16 + col) * AP + quad * 8;
    const _Float16* ap = Ap + ((size_t)(mt * KF * 64 + lane)) * 8;
#pragma unroll
    for (int kf = 0; kf < KF; ++kf) {
      const half8 av = *(const half8*)(ap + kf * 512);
      const half8 bv = *(const half8*)(bp + kf * 32);
      acc = __builtin_amdgcn_mfma_f32_16x16x32_f16(av, bv, acc, 0, 0, 0);
    }
    const int c = nt * 16 + col;
    if (c < R) {
      const int b  = c / TWOL1;
      const int o0 = mt * 16 + quad * 4;
      const half4 g4 = *(const half4*)(G + b * 264 + goff + o0);
      half4 hv;
#pragma unroll
      for (int r = 0; r < 4; ++r) hv[r] = (_Float16)(acc[r] * (float)g4[r]);
      *(half4*)(H + c * HP + o0) = hv;
    }
  }
}

// Scalar-chain layer (swapped): silu part (M=64) -> HsOut, gate part (M=256)
// -> Gout. Columns = b (8 valid of 16).
template<int K>
__device__ __forceinline__ void scal_sw(
    const _Float16* __restrict__ Bact, const _Float16* __restrict__ ApS,
    const _Float16* __restrict__ ApG, _Float16* __restrict__ HsOut,
    _Float16* __restrict__ Gout)
{
  constexpr int KF = K / 32;
  constexpr int AP = K + 8;
  const int lane = threadIdx.x & 63;
  const int wave = threadIdx.x >> 6;
  const int col  = lane & 15;
  const int quad = lane >> 4;
  const _Float16* bp = Bact + col * AP + quad * 8;
  {                                    // silu part: 4 tiles, one per wave
    const int mt = wave;
    f32x4 acc = {0.f, 0.f, 0.f, 0.f};
    const _Float16* ap = ApS + ((size_t)(mt * KF * 64 + lane)) * 8;
#pragma unroll
    for (int kf = 0; kf < KF; ++kf)
      acc = __builtin_amdgcn_mfma_f32_16x16x32_f16(
          *(const half8*)(ap + kf * 512), *(const half8*)(bp + kf * 32), acc, 0, 0, 0);
    if (col < B_ROWS) {
      const int o0 = mt * 16 + quad * 4;
      half4 hv;
#pragma unroll
      for (int r = 0; r < 4; ++r) {
        const float z = acc[r];
        hv[r] = (_Float16)(z * __builtin_amdgcn_rcpf(1.f + __expf(-z)));
      }
      *(half4*)(HsOut + col * 72 + o0) = hv;
    }
  }
  for (int mt = wave; mt < 16; mt += 4) { // gate part: 16 tiles
    f32x4 acc = {0.f, 0.f, 0.f, 0.f};
    const _Float16* ap = ApG + ((size_t)(mt * KF * 64 + lane)) * 8;
#pragma unroll
    for (int kf = 0; kf < KF; ++kf)
      acc = __builtin_amdgcn_mfma_f32_16x16x32_f16(
          *(const half8*)(ap + kf * 512), *(const half8*)(bp + kf * 32), acc, 0, 0, 0);
    if (col < B_ROWS) {
      const int o0 = mt * 16 + quad * 4;
      half4 gv;
#pragma unroll
      for (int r = 0; r < 4; ++r)
        gv[r] = (_Float16)__builtin_amdgcn_rcpf(1.f + __expf(-acc[r]));
      *(half4*)(Gout + col * 264 + o0) = gv;
    }
  }
}

// Final layer: per-(b,m) dot with w4 (uniform scalar loads), b128 H reads.
template<int TWOL1, int K>
__device__ __forceinline__ void layer4_sw(
    const _Float16* __restrict__ H, const float* __restrict__ w4, int w4off,
    float* __restrict__ out, int b0, int lsq)
{
  constexpr int R  = 8 * TWOL1;
  constexpr int HP = K + 8;
  const int r = threadIdx.x;
  if (r < R) {
    float s = 0.f;
#pragma unroll
    for (int i8 = 0; i8 < K / 8; ++i8) {
      const half8 hv = *(const half8*)(H + r * HP + i8 * 8);
#pragma unroll
      for (int j = 0; j < 8; ++j) s += (float)hv[j] * w4[w4off + i8 * 8 + j];
    }
    constexpr float scale = (K == 64) ? 0.125f : 0.17677669529663687f;
    out[(size_t)(b0 + r / TWOL1) * OUT_COLS + lsq + (r % TWOL1)] = s * scale;
  }
}

__global__ __launch_bounds__(256, 3) void fused_decoder(
    const float* __restrict__ vraw, const float* __restrict__ w4,
    const _Float16* __restrict__ packed, float* __restrict__ out)
{
  __shared__ __align__(16) _Float16 smem[SMEM_ELTS];
  _Float16* STG = smem + OFF_STG;
  _Float16* HA  = smem + OFF_HA;
  _Float16* HB  = smem + OFF_HB;
  _Float16* HsA = smem + OFF_HSA;
  _Float16* HsB = smem + OFF_HSB;
  _Float16* G1  = smem + OFF_G1;
  _Float16* G2  = smem + OFF_G2;
  _Float16* G3  = smem + OFF_G3;
  const int b0 = blockIdx.x * B_ROWS;
  const _Float16* pk = packed;
  fvec4 rA[7], rB[7];

  issue_loads<1, 256>(vraw, b0, 0, rA);
  issue_loads<3, 128>(vraw, b0, 256, rB);
  ws_l0(rA, STG);
  __syncthreads();
  // scalar chain
  scal_sw<256>(STG, pk + 0, pk + 16384, HsA, G1);
  __syncthreads();
  write_stage<3, 128>(rB, STG);
  issue_loads<5, 128>(vraw, b0, 640, rA);
  scal_sw<64>(HsA, pk + P2BASE, pk + P2BASE + 4096, HsB, G2);
  __syncthreads();
  scal_sw<64>(HsB, pk + P3BASE, pk + P3BASE + 4096, HsA, G3);
  __syncthreads();
  layer4_sw<1, 64>(HsA, w4, 0, out, b0, 0);
  // chain 1 (l=1): L1 merged into this window
  gemm_sw<3, 128, 64>(STG, pk + 81920, HA, G1, 0);
  __syncthreads();
  write_stage<5, 128>(rA, STG);
  issue_loads<7, 64>(vraw, b0, 1280, rB);
  gemm_sw<3, 64, 64>(HA, pk + P2BASE + 20480, HB, G2, 0);
  __syncthreads();
  gemm_sw<3, 64, 64>(HB, pk + P3BASE + 20480, HA, G3, 0);
  __syncthreads();
  layer4_sw<3, 64>(HA, w4, 64, out, b0, 1);
  gemm_sw<5, 128, 64>(STG, pk + 90112, HB, G1, 64);       // chain 2 L1
  __syncthreads();
  write_stage<7, 64>(rB, STG);
  issue_loads<9, 64>(vraw, b0, 1728, rA);
  gemm_sw<5, 64, 64>(HB, pk + P2BASE + 24576, HA, G2, 64);
  __syncthreads();
  gemm_sw<5, 64, 64>(HA, pk + P3BASE + 24576, HB, G3, 64);
  __syncthreads();
  layer4_sw<5, 64>(HB, w4, 128, out, b0, 4);
  gemm_sw<7, 64, 32>(STG, pk + 98304, HA, G1, 128);       // chain 3 L1
  __syncthreads();
  write_stage<9, 64>(rA, STG);
  issue_loads<11, 64>(vraw, b0, 2304, rB);
  gemm_sw<7, 32, 32>(HA, pk + P2BASE + 28672, HB, G2, 128);
  __syncthreads();
  gemm_sw<7, 32, 32>(HB, pk + P3BASE + 28672, HA, G3, 128);
  __syncthreads();
  layer4_sw<7, 32>(HA, w4, 192, out, b0, 9);
  gemm_sw<9, 64, 32>(STG, pk + 100352, HB, G1, 160);      // chain 4 L1
  __syncthreads();
  write_stage<11, 64>(rB, STG);
  issue_loads<13, 64>(vraw, b0, 3008, rA);
  gemm_sw<9, 32, 32>(HB, pk + P2BASE + 29696, HA, G2, 160);
  __syncthreads();
  gemm_sw<9, 32, 32>(HA, pk + P3BASE + 29696, HB, G3, 160);
  __syncthreads();
  layer4_sw<9, 32>(HB, w4, 224, out, b0, 16);
  gemm_sw<11, 64, 32>(STG, pk + 102400, HA, G1, 192);     // chain 5 L1
  __syncthreads();
  write_stage<13, 64>(rA, STG);
  gemm_sw<11, 32, 32>(HA, pk + P2BASE + 30720, HB, G2, 192);
  __syncthreads();
  gemm_sw<11, 32, 32>(HB, pk + P3BASE + 30720, HA, G3, 192);
  __syncthreads();
  layer4_sw<11, 32>(HA, w4, 256, out, b0, 25);
  gemm_sw<13, 64, 32>(STG, pk + 104448, HB, G1, 224);     // chain 6 L1
  __syncthreads();
  gemm_sw<13, 32, 32>(HB, pk + P2BASE + 31744, HA, G2, 224);
  __syncthreads();
  gemm_sw<13, 32, 32>(HA, pk + P3BASE + 31744, HB, G3, 224);
  __syncthreads();
  layer4_sw<13, 32>(HB, w4, 288, out, b0, 36);
}

extern "C" void kernel_launch(void* const* d_in, const int* in_sizes, int n_in,
                              void* d_out, int out_size, void* d_ws, size_t ws_size,
                              hipStream_t stream)
{
  (void)in_sizes; (void)n_in; (void)out_size; (void)ws_size;
  const float* vraw = (const float*)d_in[0];
  const float* w1   = (const float*)d_in[1];
  const float* w2   = (const float*)d_in[2];
  const float* w3   = (const float*)d_in[3];
  const float* w4   = (const float*)d_in[4];
  float* out = (float*)d_out;
  _Float16* packed = (_Float16*)d_ws;   // 172032 elems = 344064 B

  prep_weights<<<84, 256, 0, stream>>>(w1, w2, w3, packed);
  fused_decoder<<<16384 / B_ROWS, 256, 0, stream>>>(vraw, w4, packed, out);
}